// Round 2
// baseline (212.248 us; speedup 1.0000x reference)
//
#include <hip/hip_runtime.h>

// Scatter-permute: out[expert_offsets[expert_idx[t]] + slot_idx[t], :] = token_hidden[t, :]
// T=65536 tokens, D=2048 f32 (8 KB/row). rows form a bijection over [0,T) ->
// every output row is written exactly once, so no zero-init of d_out is needed.
//
// Memory-bound: 1.074 GB total traffic, copy ceiling ~6.3 TB/s -> ~170 us floor.
// R1 (1 block/row, plain loads/stores): 206 us = 5.2 TB/s.
// R2: grid-stride persistent blocks + nontemporal loads/stores to keep the
// two 512 MB single-use streams from churning L2 and to amortize the
// dependent index-load chain across 16 rows/block.

typedef float f32x4 __attribute__((ext_vector_type(4)));

__global__ void __launch_bounds__(256)
scatter_rows_kernel(const f32x4* __restrict__ src,
                    const int* __restrict__ expert_idx,
                    const int* __restrict__ slot_idx,
                    const int* __restrict__ expert_offsets,
                    f32x4* __restrict__ dst,
                    int nrows)
{
    // D = 2048 f32 -> 512 f32x4 per row; 256 threads -> 2 vectors per lane.
    const int tid = threadIdx.x;

    for (int t = blockIdx.x; t < nrows; t += gridDim.x) {
        // Index chain: two small cached loads (expert_idx/slot_idx are
        // sequential within the block's stride; expert_offsets is 65 ints).
        const int row = expert_offsets[expert_idx[t]] + slot_idx[t];

        const f32x4* s = src + (size_t)t   * 512;
        f32x4*       d = dst + (size_t)row * 512;

        // Issue both loads before the stores; nontemporal keeps the
        // single-use streams out of L2's way.
        f32x4 a = __builtin_nontemporal_load(&s[tid]);
        f32x4 b = __builtin_nontemporal_load(&s[tid + 256]);
        __builtin_nontemporal_store(a, &d[tid]);
        __builtin_nontemporal_store(b, &d[tid + 256]);
    }
}

extern "C" void kernel_launch(void* const* d_in, const int* in_sizes, int n_in,
                              void* d_out, int out_size, void* d_ws, size_t ws_size,
                              hipStream_t stream) {
    const float* token_hidden   = (const float*)d_in[0];
    const int*   expert_idx     = (const int*)  d_in[1];
    const int*   slot_idx       = (const int*)  d_in[2];
    const int*   expert_offsets = (const int*)  d_in[3];

    const int T = in_sizes[1];            // 65536 tokens (rows)

    // 4096 blocks = 16 rows/block; 2048 concurrently resident (8 blocks/CU
    // at 256 threads), so ~2 generations -- enough blocks to fill, few
    // enough to amortize the per-row index chain.
    scatter_rows_kernel<<<4096, 256, 0, stream>>>(
        (const f32x4*)token_hidden, expert_idx, slot_idx, expert_offsets,
        (f32x4*)d_out, T);
}